// Round 1
// baseline (4866.206 us; speedup 1.0000x reference)
//
#include <hip/hip_runtime.h>

// LIIF local-ensemble upsampling, fp32 baseline.
// B=4, C=64, H=W=64 -> h_out=w_out=256. MLP: 66 -> 256 -> 256 -> 64.
// One 256-thread WG handles 32 consecutive queries (one b), all 4 corners.

#define MT   32      // query rows per workgroup
#define CCH  64      // channels
#define HID  256     // hidden dim
#define K1   66      // C + 2

__global__ __launch_bounds__(256, 2) void liif_fp32_kernel(
    const float* __restrict__ x,  const float* __restrict__ W1, const float* __restrict__ b1,
    const float* __restrict__ W2, const float* __restrict__ b2,
    const float* __restrict__ W3, const float* __restrict__ b3,
    float* __restrict__ out)
{
    __shared__ float inp[MT][K1 + 2];   // 32 x 68 (row stride 272B, 16B aligned)
    __shared__ float h1[MT][HID];       // 32 KB
    __shared__ float h2[MT][HID];       // 32 KB
    __shared__ int   s_iy[4][MT], s_ix[4][MT];
    __shared__ float s_rely[4][MT], s_relx[4][MT], s_w[4][MT];

    const int tid   = threadIdx.x;
    const int bq    = blockIdx.x;          // 0..8191
    const int b     = bq >> 11;            // / 2048 tiles per batch
    const int qBase = (bq & 2047) * MT;

    // Per-row query geometry for all 4 corners (one thread per row).
    if (tid < MT) {
        const int q  = qBase + tid;
        const int yq = q >> 8, xq = q & 255;
        const float cy  = -1.0f + (2.0f * yq + 1.0f) / 256.0f;
        const float cx  = -1.0f + (2.0f * xq + 1.0f) / 256.0f;
        const float lim = 1.0f - 1e-6f;
        float area[4];
        #pragma unroll
        for (int c = 0; c < 4; ++c) {
            const float vx = (c & 2) ? 1.0f : -1.0f;   // applied to height coord
            const float vy = (c & 1) ? 1.0f : -1.0f;   // applied to width coord
            float sy = cy + vx * (1.0f / 64.0f) + 1e-6f;
            float sx = cx + vy * (1.0f / 64.0f) + 1e-6f;
            sy = fminf(fmaxf(sy, -lim), lim);
            sx = fminf(fmaxf(sx, -lim), lim);
            int iy = (int)rintf(((sy + 1.0f) * 64.0f - 1.0f) * 0.5f);  // round-half-even = jnp.round
            int ix = (int)rintf(((sx + 1.0f) * 64.0f - 1.0f) * 0.5f);
            iy = min(max(iy, 0), 63);
            ix = min(max(ix, 0), 63);
            const float fy = -1.0f + (2.0f * iy + 1.0f) / 64.0f;
            const float fx = -1.0f + (2.0f * ix + 1.0f) / 64.0f;
            const float ry = (cy - fy) * 64.0f;
            const float rx = (cx - fx) * 64.0f;
            s_iy[c][tid] = iy;  s_ix[c][tid] = ix;
            s_rely[c][tid] = ry; s_relx[c][tid] = rx;
            area[c] = fabsf(ry * rx) + 1e-9f;
        }
        const float tot = area[0] + area[1] + area[2] + area[3];
        // local_ensemble swap 0<->3, 1<->2: pred[c] weighted by area[3-c]
        #pragma unroll
        for (int c = 0; c < 4; ++c) s_w[c][tid] = area[3 - c] / tot;
    }
    __syncthreads();

    float out_acc[8];
    #pragma unroll
    for (int j = 0; j < 8; ++j) out_acc[j] = 0.0f;
    const int n3 = tid & 63;   // output channel for layer3
    const int rg = tid >> 6;   // row group 0..3 for layer3

    for (int c = 0; c < 4; ++c) {
        // ---- gather inp[row][0..65] ----
        {
            const int row = tid >> 3;          // 0..31
            const int ch0 = (tid & 7) * 8;     // 8 channels per thread
            const int iy = s_iy[c][row], ix = s_ix[c][row];
            const float* xb = x + (((size_t)b * CCH) * 64 + iy) * 64 + ix;
            #pragma unroll
            for (int j = 0; j < 8; ++j)
                inp[row][ch0 + j] = xb[(size_t)(ch0 + j) * 4096];
            if ((tid & 7) == 0) inp[row][64] = s_rely[c][row];
            if ((tid & 7) == 1) inp[row][65] = s_relx[c][row];
        }
        __syncthreads();

        // ---- layer 1: h1 = relu(inp @ W1 + b1), thread = neuron ----
        {
            const int n = tid;
            const float bias = b1[n];
            for (int rb = 0; rb < MT; rb += 8) {
                float acc[8];
                #pragma unroll
                for (int j = 0; j < 8; ++j) acc[j] = bias;
                #pragma unroll 2
                for (int k = 0; k < K1; ++k) {
                    const float w = W1[k * HID + n];
                    #pragma unroll
                    for (int j = 0; j < 8; ++j)
                        acc[j] = fmaf(inp[rb + j][k], w, acc[j]);
                }
                #pragma unroll
                for (int j = 0; j < 8; ++j)
                    h1[rb + j][n] = fmaxf(acc[j], 0.0f);
            }
        }
        __syncthreads();

        // ---- layer 2: h2 = relu(h1 @ W2 + b2) ----
        {
            const int n = tid;
            const float bias = b2[n];
            for (int rb = 0; rb < MT; rb += 8) {
                float acc[8];
                #pragma unroll
                for (int j = 0; j < 8; ++j) acc[j] = bias;
                #pragma unroll 4
                for (int k = 0; k < HID; ++k) {
                    const float w = W2[k * HID + n];
                    #pragma unroll
                    for (int j = 0; j < 8; ++j)
                        acc[j] = fmaf(h1[rb + j][k], w, acc[j]);
                }
                #pragma unroll
                for (int j = 0; j < 8; ++j)
                    h2[rb + j][n] = fmaxf(acc[j], 0.0f);
            }
        }
        __syncthreads();

        // ---- layer 3 + corner-weighted accumulation ----
        {
            const float bias = b3[n3];
            const int r0 = rg * 8;
            float acc[8];
            #pragma unroll
            for (int j = 0; j < 8; ++j) acc[j] = bias;
            #pragma unroll 4
            for (int k = 0; k < HID; ++k) {
                const float w = W3[k * CCH + n3];
                #pragma unroll
                for (int j = 0; j < 8; ++j)
                    acc[j] = fmaf(h2[r0 + j][k], w, acc[j]);
            }
            #pragma unroll
            for (int j = 0; j < 8; ++j)
                out_acc[j] = fmaf(acc[j], s_w[c][r0 + j], out_acc[j]);
        }
        __syncthreads();   // protect inp/h1/h2 before next corner
    }

    // ---- write out[b][q][c], coalesced over the 64 channels ----
    {
        const int r0 = rg * 8;
        #pragma unroll
        for (int j = 0; j < 8; ++j) {
            const size_t q = (size_t)qBase + r0 + j;
            out[((size_t)b * 65536 + q) * 64 + n3] = out_acc[j];
        }
    }
}

extern "C" void kernel_launch(void* const* d_in, const int* in_sizes, int n_in,
                              void* d_out, int out_size, void* d_ws, size_t ws_size,
                              hipStream_t stream) {
    const float* x  = (const float*)d_in[0];
    const float* W1 = (const float*)d_in[1];
    const float* b1 = (const float*)d_in[2];
    const float* W2 = (const float*)d_in[3];
    const float* b2 = (const float*)d_in[4];
    const float* W3 = (const float*)d_in[5];
    const float* b3 = (const float*)d_in[6];
    float* out = (float*)d_out;

    const int nblocks = 4 * (65536 / MT);   // 8192
    liif_fp32_kernel<<<nblocks, 256, 0, stream>>>(x, W1, b1, W2, b2, W3, b3, out);
}

// Round 2
// 885.573 us; speedup vs baseline: 5.4950x; 5.4950x over previous
//
#include <hip/hip_runtime.h>

// LIIF local-ensemble upsampling — bf16 MFMA version.
// B=4, C=64, H=W=64 -> 256x256. MLP 66->256->256->64, fp32 accumulate.
// WG = 256 threads (4 waves) = 64 queries x 4 corners.
// Weights pre-converted to bf16 and pre-swizzled into per-lane MFMA B-fragment
// order in d_ws by a prep kernel (fully coalesced 16B/lane loads in main loop).

typedef __bf16 bf16x8 __attribute__((ext_vector_type(8)));
typedef float  f32x4  __attribute__((ext_vector_type(4)));

#define LDS_SWZ(row, kbyte) ((kbyte) ^ (((row) & 7) << 4))

// ws layout (ushort elements): W1p 48 frag-blocks, W2p 128, W3p 32 (1KB each)
#define WP1_U 0
#define WP2_U (48 * 512)
#define WP3_U (176 * 512)

// ---------------- weight prep: fp32 [K][N] -> bf16 B-fragments ----------------
// frag block layout: [ks][ntile][lane][8]  (lane l: k = ks*32+(l>>4)*8+j, n = nt*16+(l&15))
__global__ __launch_bounds__(64) void prep_weights(
    const float* __restrict__ W1, const float* __restrict__ W2,
    const float* __restrict__ W3, ushort* __restrict__ ws)
{
    const int blk = blockIdx.x;    // 0..207
    const int l   = threadIdx.x;   // 0..63
    const float* W; int Kreal, N, ks, nt; size_t off;
    if (blk < 48)       { W = W1; Kreal = 66;  N = 256; ks = blk >> 4;  nt = blk & 15; off = WP1_U + (size_t)blk * 512; }
    else if (blk < 176) { int b2 = blk - 48;  W = W2; Kreal = 256; N = 256; ks = b2 >> 4; nt = b2 & 15; off = WP2_U + (size_t)b2 * 512; }
    else                { int b3 = blk - 176; W = W3; Kreal = 256; N = 64;  ks = b3 >> 2; nt = b3 & 3;  off = WP3_U + (size_t)b3 * 512; }

    const int n = nt * 16 + (l & 15);
    ushort v[8];
    #pragma unroll
    for (int j = 0; j < 8; ++j) {
        const int k = ks * 32 + ((l >> 4) * 8) + j;
        const float f = (k < Kreal) ? W[(size_t)k * N + n] : 0.0f;
        v[j] = __builtin_bit_cast(ushort, (__bf16)f);
    }
    *(uint4*)(ws + off + (size_t)l * 8) = *(const uint4*)v;
}

// ---------------- generic hidden layer: LDS(src) x Wp -> LDS(dst) ----------------
// src: swizzled bf16 tile [64 rows][SRC_STRIDE bytes]; dst: [64][512B], relu(acc+bias)
template<int KSTEPS, int SRC_STRIDE>
__device__ inline void layer_fwd(const char* __restrict__ src, char* __restrict__ dst,
                                 const ushort* __restrict__ wp,
                                 const float* __restrict__ bias, int lane, int wv)
{
    const int lrow = lane & 15;
    const int lk   = lane >> 4;
    f32x4 acc[4][4];
    #pragma unroll
    for (int mt = 0; mt < 4; ++mt)
        #pragma unroll
        for (int nt = 0; nt < 4; ++nt)
            acc[mt][nt] = (f32x4){0.f, 0.f, 0.f, 0.f};

    #pragma unroll
    for (int ks = 0; ks < KSTEPS; ++ks) {
        bf16x8 a[4], bb[4];
        #pragma unroll
        for (int mt = 0; mt < 4; ++mt) {
            const int row   = mt * 16 + lrow;
            const int kbyte = ks * 64 + lk * 16;
            a[mt] = *(const bf16x8*)(src + row * SRC_STRIDE + LDS_SWZ(row, kbyte));
        }
        #pragma unroll
        for (int nt = 0; nt < 4; ++nt) {
            const int ntg = wv * 4 + nt;
            bb[nt] = *(const bf16x8*)(wp + (((size_t)(ks * 16 + ntg)) << 9) + (lane << 3));
        }
        #pragma unroll
        for (int mt = 0; mt < 4; ++mt)
            #pragma unroll
            for (int nt = 0; nt < 4; ++nt)
                acc[mt][nt] = __builtin_amdgcn_mfma_f32_16x16x32_bf16(a[mt], bb[nt], acc[mt][nt], 0, 0, 0);
    }

    #pragma unroll
    for (int nt = 0; nt < 4; ++nt) {
        const int n  = wv * 64 + nt * 16 + lrow;
        const float bs = bias[n];
        const int kbyte = 2 * n;
        #pragma unroll
        for (int mt = 0; mt < 4; ++mt) {
            #pragma unroll
            for (int r = 0; r < 4; ++r) {
                const int row = mt * 16 + lk * 4 + r;
                const float v = fmaxf(acc[mt][nt][r] + bs, 0.0f);
                *(ushort*)(dst + row * 512 + LDS_SWZ(row, kbyte)) = __builtin_bit_cast(ushort, (__bf16)v);
            }
        }
    }
}

// ---------------- main kernel ----------------
__global__ __launch_bounds__(256, 2) void liif_mfma_kernel(
    const float* __restrict__ x,
    const float* __restrict__ b1f, const float* __restrict__ b2f, const float* __restrict__ b3f,
    const ushort* __restrict__ ws, float* __restrict__ out)
{
    __shared__ char bufA[32 * 1024];   // inp (16KB, stride 256B) then h2 (32KB, stride 512B)
    __shared__ char bufB[32 * 1024];   // h1 (stride 512B)
    __shared__ int   s_iy[4][64], s_ix[4][64];
    __shared__ float s_rely[4][64], s_relx[4][64], s_w[4][64];

    const int tid  = threadIdx.x;
    const int lane = tid & 63;
    const int wv   = tid >> 6;          // 0..3
    const int lrow = lane & 15;
    const int lk   = lane >> 4;
    const int bq   = blockIdx.x;        // 0..4095
    const int b    = bq >> 10;
    const int q0   = (bq & 1023) << 6;  // 64 queries per WG

    // ---- per-query geometry, all 4 corners ----
    if (tid < 64) {
        const int q  = q0 + tid;
        const int yq = q >> 8, xq = q & 255;
        const float cy  = -1.0f + (2.0f * yq + 1.0f) / 256.0f;
        const float cx  = -1.0f + (2.0f * xq + 1.0f) / 256.0f;
        const float lim = 1.0f - 1e-6f;
        float area[4];
        #pragma unroll
        for (int c = 0; c < 4; ++c) {
            const float vx = (c & 2) ? 1.0f : -1.0f;
            const float vy = (c & 1) ? 1.0f : -1.0f;
            float sy = cy + vx * (1.0f / 64.0f) + 1e-6f;
            float sx = cx + vy * (1.0f / 64.0f) + 1e-6f;
            sy = fminf(fmaxf(sy, -lim), lim);
            sx = fminf(fmaxf(sx, -lim), lim);
            int iy = (int)rintf(((sy + 1.0f) * 64.0f - 1.0f) * 0.5f);
            int ix = (int)rintf(((sx + 1.0f) * 64.0f - 1.0f) * 0.5f);
            iy = min(max(iy, 0), 63);
            ix = min(max(ix, 0), 63);
            const float fy = -1.0f + (2.0f * iy + 1.0f) / 64.0f;
            const float fx = -1.0f + (2.0f * ix + 1.0f) / 64.0f;
            const float ry = (cy - fy) * 64.0f;
            const float rx = (cx - fx) * 64.0f;
            s_iy[c][tid] = iy;   s_ix[c][tid] = ix;
            s_rely[c][tid] = ry; s_relx[c][tid] = rx;
            area[c] = fabsf(ry * rx) + 1e-9f;
        }
        const float tot = area[0] + area[1] + area[2] + area[3];
        #pragma unroll
        for (int c = 0; c < 4; ++c) s_w[c][tid] = area[3 - c] / tot;   // 0<->3, 1<->2 swap
    }
    __syncthreads();

    float oacc[4][4];
    #pragma unroll
    for (int mt = 0; mt < 4; ++mt)
        #pragma unroll
        for (int r = 0; r < 4; ++r) oacc[mt][r] = 0.0f;

    for (int c = 0; c < 4; ++c) {
        // ---- stage inp tile: bufA rows 0..63, stride 256B, swizzled, K padded to 96 ----
        {
            const int r = tid >> 2, p = tid & 3;
            const int iy = s_iy[c][r], ix = s_ix[c][r];
            const float* xb = x + (((size_t)b * 64) * 64 + iy) * 64 + ix;
            #pragma unroll
            for (int half = 0; half < 2; ++half) {
                ushort tmp[8];
                #pragma unroll
                for (int j = 0; j < 8; ++j) {
                    const float f = xb[(size_t)(p * 16 + half * 8 + j) * 4096];
                    tmp[j] = __builtin_bit_cast(ushort, (__bf16)f);
                }
                const int kbyte = p * 32 + half * 16;
                *(uint4*)(bufA + r * 256 + LDS_SWZ(r, kbyte)) = *(const uint4*)tmp;
            }
            ushort pad[8] = {0, 0, 0, 0, 0, 0, 0, 0};
            if (p == 0) {
                pad[0] = __builtin_bit_cast(ushort, (__bf16)s_rely[c][r]);
                pad[1] = __builtin_bit_cast(ushort, (__bf16)s_relx[c][r]);
            }
            const int kbyte = 128 + p * 16;
            *(uint4*)(bufA + r * 256 + LDS_SWZ(r, kbyte)) = *(const uint4*)pad;
        }
        __syncthreads();

        // ---- layer 1: inp(bufA) -> h1(bufB) ----
        layer_fwd<3, 256>(bufA, bufB, ws + WP1_U, b1f, lane, wv);
        __syncthreads();

        // ---- layer 2: h1(bufB) -> h2(bufA) ----
        layer_fwd<8, 512>(bufB, bufA, ws + WP2_U, b2f, lane, wv);
        __syncthreads();

        // ---- layer 3: h2(bufA) -> weighted out accumulation (N=16 per wave) ----
        {
            f32x4 acc3[4];
            #pragma unroll
            for (int mt = 0; mt < 4; ++mt) acc3[mt] = (f32x4){0.f, 0.f, 0.f, 0.f};
            #pragma unroll
            for (int ks = 0; ks < 8; ++ks) {
                bf16x8 a[4];
                #pragma unroll
                for (int mt = 0; mt < 4; ++mt) {
                    const int row   = mt * 16 + lrow;
                    const int kbyte = ks * 64 + lk * 16;
                    a[mt] = *(const bf16x8*)(bufA + row * 512 + LDS_SWZ(row, kbyte));
                }
                const bf16x8 bb = *(const bf16x8*)(ws + WP3_U + (((size_t)(ks * 4 + wv)) << 9) + (lane << 3));
                #pragma unroll
                for (int mt = 0; mt < 4; ++mt)
                    acc3[mt] = __builtin_amdgcn_mfma_f32_16x16x32_bf16(a[mt], bb, acc3[mt], 0, 0, 0);
            }
            const float bs = b3f[wv * 16 + lrow];
            #pragma unroll
            for (int mt = 0; mt < 4; ++mt) {
                #pragma unroll
                for (int r = 0; r < 4; ++r) {
                    const int row = mt * 16 + lk * 4 + r;
                    oacc[mt][r] += (acc3[mt][r] + bs) * s_w[c][row];
                }
            }
        }
        __syncthreads();   // protect bufA/bufB before next corner
    }

    // ---- store out[b][q][ch] fp32 ----
    #pragma unroll
    for (int mt = 0; mt < 4; ++mt) {
        #pragma unroll
        for (int r = 0; r < 4; ++r) {
            const int q = q0 + mt * 16 + lk * 4 + r;
            out[((size_t)b * 65536 + q) * 64 + wv * 16 + lrow] = oacc[mt][r];
        }
    }
}

extern "C" void kernel_launch(void* const* d_in, const int* in_sizes, int n_in,
                              void* d_out, int out_size, void* d_ws, size_t ws_size,
                              hipStream_t stream) {
    const float* x  = (const float*)d_in[0];
    const float* W1 = (const float*)d_in[1];
    const float* b1 = (const float*)d_in[2];
    const float* W2 = (const float*)d_in[3];
    const float* b2 = (const float*)d_in[4];
    const float* W3 = (const float*)d_in[5];
    const float* b3 = (const float*)d_in[6];
    float* out = (float*)d_out;
    ushort* wp = (ushort*)d_ws;

    prep_weights<<<208, 64, 0, stream>>>(W1, W2, W3, wp);
    liif_mfma_kernel<<<4096, 256, 0, stream>>>(x, b1, b2, b3, wp, out);
}